// Round 9
// baseline (163.484 us; speedup 1.0000x reference)
//
#include <hip/hip_runtime.h>
#include <hip/hip_bf16.h>

// Block-sparse attention: B=2, S=4096, H=16, D=128, BS=64, LOCAL=8, GLOBAL=1.
// fp32 in/out, bf16 MFMA, flash online softmax (exp2 domain).
// Round 9: 2 q-blocks per workgroup (wave owns 16 rows of block 2g AND 2g+1),
// shared K/V LDS reads feed both blocks' MFMAs -> LDS read volume and staging
// per FLOP halved. Union KV window staged once. Extended vt_swz (stores 2-way).

typedef __bf16 bf16_t;
typedef bf16_t bf16x8 __attribute__((ext_vector_type(8)));
typedef bf16_t bf16x4 __attribute__((ext_vector_type(4)));
typedef float f32x4 __attribute__((ext_vector_type(4)));
typedef uint32_t u32x4 __attribute__((ext_vector_type(4)));

#define DIM 128
#define NH 16
#define SEQ 4096
#define ROWSTRIDE (NH * DIM)

// Kb: [64][128] bf16, A = row*256 + col*2. Fold row low-3 bits into chunk bits.
__device__ __forceinline__ uint32_t kb_swz(uint32_t A) {
    return A ^ (((A >> 8) & 7u) << 4);
}
// Vt: [128][64] bf16, A = d*128 + k*2. Reads (lanes vary d) 2-way; with the
// bit12 term the stores (lanes vary sc4 = d/4) are 2-way as well.
__device__ __forceinline__ uint32_t vt_swz(uint32_t A) {
    return A ^ (((A >> 9) & 7u) << 4) ^ (((A >> 8) & 1u) << 6) ^ (((A >> 12) & 1u) << 7);
}

// Register exchange: from per-lane P row chunks ch[8] (q=lr, k=16n+4lk+{0..3})
// to PV A-fragments paf[kk] = P[q=lr][k=32kk+8lk+0..7]. (verified r8)
__device__ __forceinline__ void exchange_paf(const uint32_t ch[8], int lr, int lk,
                                             bf16x8 paf[2]) {
    const int s0 = lr + 32 * (lk & 1);
    const bool hi = (lk & 2) != 0;
    #pragma unroll
    for (int kk = 0; kk < 2; ++kk) {
        uint32_t res[4];
        #pragma unroll
        for (int u = 0; u < 2; ++u) {
            const uint32_t a0 = (uint32_t)__shfl((int)ch[4 * kk + u],     s0);
            const uint32_t b0 = (uint32_t)__shfl((int)ch[4 * kk + 2 + u], s0);
            const uint32_t a1 = (uint32_t)__shfl((int)ch[4 * kk + u],     s0 + 16);
            const uint32_t b1 = (uint32_t)__shfl((int)ch[4 * kk + 2 + u], s0 + 16);
            res[u]     = hi ? b0 : a0;
            res[2 + u] = hi ? b1 : a1;
        }
        u32x4 tv = {res[0], res[1], res[2], res[3]};
        paf[kk] = *(bf16x8*)&tv;
    }
}

__global__ __launch_bounds__(256) void sparse_attn_kernel(
    const float* __restrict__ q, const float* __restrict__ k,
    const float* __restrict__ v, float* __restrict__ out)
{
    __shared__ __align__(16) bf16_t Kb[64 * DIM];       // 16384 B
    __shared__ __align__(16) bf16_t Vt[DIM * 64];       // 16384 B (total 32768)

    // XCD-aware swizzle: 1024 wgs, 8 XCDs -> contiguous 128-chunk per XCD.
    const int L  = ((blockIdx.x & 7) << 7) | (blockIdx.x >> 3);
    const int g  = L & 31;           // q-block pair: blocks 2g, 2g+1
    const int h  = (L >> 5) & 15;
    const int b  = L >> 9;
    const int qiA = 2 * g;
    const int qiB = 2 * g + 1;

    const int tid  = threadIdx.x;
    const int wave = tid >> 6;
    const int lane = tid & 63;
    const int lr = lane & 15;
    const int lk = lane >> 4;

    const int sc4 = tid & 31;   // staging: float4 column 0..31
    const int sr  = tid >> 5;   // staging: row group 0..7

    const float scale2 = 0.12751649736230476f;  // (1/sqrt(128)) * log2(e)

    const size_t bh_off = ((size_t)b * SEQ * NH + (size_t)h) * DIM;
    const float* kbh = k + bh_off;
    const float* vbh = v + bh_off;

    // ---- Q fragments for both blocks, pre-scaled ----
    bf16x8 qfA[4], qfB[4];
    #pragma unroll
    for (int blk = 0; blk < 2; ++blk) {
        const int qi = blk ? qiB : qiA;
        const float* qrow = q + bh_off + (size_t)(qi * 64 + wave * 16 + lr) * ROWSTRIDE;
        #pragma unroll
        for (int kk = 0; kk < 4; ++kk) {
            const float4 a0 = *(const float4*)(qrow + 32 * kk + 8 * lk);
            const float4 a1 = *(const float4*)(qrow + 32 * kk + 8 * lk + 4);
            bf16x8 f;
            f[0] = (bf16_t)(a0.x * scale2); f[1] = (bf16_t)(a0.y * scale2);
            f[2] = (bf16_t)(a0.z * scale2); f[3] = (bf16_t)(a0.w * scale2);
            f[4] = (bf16_t)(a1.x * scale2); f[5] = (bf16_t)(a1.y * scale2);
            f[6] = (bf16_t)(a1.z * scale2); f[7] = (bf16_t)(a1.w * scale2);
            if (blk) qfB[kk] = f; else qfA[kk] = f;
        }
    }

    f32x4 oA[8], oB[8];
    #pragma unroll
    for (int n = 0; n < 8; ++n) {
        oA[n] = (f32x4){0.f, 0.f, 0.f, 0.f};
        oB[n] = (f32x4){0.f, 0.f, 0.f, 0.f};
    }
    float mrunA = -3.0e38f, lrunA = 0.f;
    float mrunB = -3.0e38f, lrunB = 0.f;
    const int qrow_local = wave * 16 + lr;   // lane's q row within its 64-block

    // Union KV window of {2g, 2g+1}: {0} U [lo, 2g+1]
    const int lo  = (2 * g - 7 > 1) ? (2 * g - 7) : 1;
    const int nit = 2 * g + 3 - lo;

    float4 kreg[8];   // K rows (8i+sr)          (one iter ahead)
    float4 vreg[8];   // V rows 4*(sr+8*T)+i     (same iter)

    #define LOAD_K(jb)                                                            \
    {                                                                             \
        const float* kb_ = kbh + (size_t)((jb) * 64) * ROWSTRIDE + 4 * sc4;       \
        _Pragma("unroll")                                                         \
        for (int i = 0; i < 8; ++i)                                               \
            kreg[i] = *(const float4*)(kb_ + (size_t)(8 * i + sr) * ROWSTRIDE);   \
    }
    #define LOAD_V(jb)                                                            \
    {                                                                             \
        const float* vb_ = vbh + (size_t)((jb) * 64) * ROWSTRIDE + 4 * sc4;       \
        _Pragma("unroll")                                                         \
        for (int T = 0; T < 2; ++T)                                               \
            _Pragma("unroll")                                                     \
            for (int i = 0; i < 4; ++i)                                           \
                vreg[T * 4 + i] = *(const float4*)(vb_ +                          \
                    (size_t)(4 * (sr + 8 * T) + i) * ROWSTRIDE);                  \
    }

    // softmax + P-pack + exchange for one block (wg-uniform gating outside)
    #define SOFTMAX_EXCH(sX, mrunX, lrunX, oX, pafX, diagX)                       \
    {                                                                             \
        if (diagX) {                                                              \
            _Pragma("unroll")                                                     \
            for (int n = 0; n < 4; ++n)                                           \
                _Pragma("unroll")                                                 \
                for (int r = 0; r < 4; ++r)                                       \
                    if (16 * n + 4 * lk + r > qrow_local) sX[n][r] = -1.0e30f;    \
        }                                                                         \
        float vmax = -3.0e38f;                                                    \
        _Pragma("unroll")                                                         \
        for (int n = 0; n < 4; ++n)                                               \
            _Pragma("unroll")                                                     \
            for (int r = 0; r < 4; ++r) vmax = fmaxf(vmax, sX[n][r]);             \
        vmax = fmaxf(vmax, __shfl_xor(vmax, 16));                                 \
        vmax = fmaxf(vmax, __shfl_xor(vmax, 32));                                 \
        if (!__all(vmax - mrunX <= 8.0f)) {                                       \
            const float mnew = fmaxf(mrunX, vmax);                                \
            const float alpha = exp2f(mrunX - mnew);                              \
            mrunX = mnew;                                                         \
            lrunX *= alpha;                                                       \
            float av[4];                                                          \
            _Pragma("unroll")                                                     \
            for (int r = 0; r < 4; ++r) av[r] = __shfl(alpha, 4 * lk + r);        \
            _Pragma("unroll")                                                     \
            for (int n = 0; n < 8; ++n)                                           \
                _Pragma("unroll")                                                 \
                for (int r = 0; r < 4; ++r) oX[n][r] *= av[r];                    \
        }                                                                         \
        uint32_t ch[8];                                                           \
        _Pragma("unroll")                                                         \
        for (int n = 0; n < 4; ++n) {                                             \
            float p0 = exp2f(sX[n][0] - mrunX);                                   \
            float p1 = exp2f(sX[n][1] - mrunX);                                   \
            float p2 = exp2f(sX[n][2] - mrunX);                                   \
            float p3 = exp2f(sX[n][3] - mrunX);                                   \
            lrunX += (p0 + p1) + (p2 + p3);                                       \
            bf16x4 c4 = {(bf16_t)p0, (bf16_t)p1, (bf16_t)p2, (bf16_t)p3};         \
            uint32_t* cw = (uint32_t*)&c4;                                        \
            ch[2 * n]     = cw[0];                                                \
            ch[2 * n + 1] = cw[1];                                                \
        }                                                                         \
        exchange_paf(ch, lr, lk, pafX);                                           \
    }

    LOAD_K(0);  // j_of(0) == 0

    for (int t = 0; t < nit; ++t) {
        const int j = (t == 0) ? 0 : (lo + t - 1);
        const bool actA = (j == 0) || (j >= qiA - 7 && j <= qiA);
        const bool actB = (j == 0) || (j >= qiB - 7 && j <= qiB);

        // ---- issue V loads for THIS block (consumed after QK^T below) ----
        LOAD_V(j);

        // ---- Kb write from kreg ----
        #pragma unroll
        for (int i = 0; i < 8; ++i) {
            const float4 t4 = kreg[i];
            bf16x4 c = {(bf16_t)t4.x, (bf16_t)t4.y, (bf16_t)t4.z, (bf16_t)t4.w};
            const uint32_t A = kb_swz((uint32_t)((8 * i + sr) * 256 + 8 * sc4));
            *(bf16x4*)((char*)Kb + A) = c;
        }
        __syncthreads();

        // ---- S^T = K*Q^T for BOTH blocks; kf read once, used twice ----
        f32x4 sA[4], sB[4];
        __builtin_amdgcn_s_setprio(1);
        #pragma unroll
        for (int n = 0; n < 4; ++n) {
            f32x4 a = (f32x4){0.f, 0.f, 0.f, 0.f};
            f32x4 c = (f32x4){0.f, 0.f, 0.f, 0.f};
            #pragma unroll
            for (int kk = 0; kk < 4; ++kk) {
                const uint32_t A = kb_swz((uint32_t)((16 * n + lr) * 256 + 64 * kk + 16 * lk));
                bf16x8 kf = *(const bf16x8*)((const char*)Kb + A);
                a = __builtin_amdgcn_mfma_f32_16x16x32_bf16(kf, qfA[kk], a, 0, 0, 0);
                c = __builtin_amdgcn_mfma_f32_16x16x32_bf16(kf, qfB[kk], c, 0, 0, 0);
            }
            sA[n] = a;
            sB[n] = c;
        }
        __builtin_amdgcn_s_setprio(0);

        // ---- Vt write from vreg (vreg dies here) ----
        #pragma unroll
        for (int T = 0; T < 2; ++T) {
            #pragma unroll
            for (int j2 = 0; j2 < 4; ++j2) {
                const int d = 4 * sc4 + j2;
                bf16x4 c = {(bf16_t)((const float*)&vreg[T * 4 + 0])[j2],
                            (bf16_t)((const float*)&vreg[T * 4 + 1])[j2],
                            (bf16_t)((const float*)&vreg[T * 4 + 2])[j2],
                            (bf16_t)((const float*)&vreg[T * 4 + 3])[j2]};
                const uint32_t A = vt_swz((uint32_t)(d * 128 + 8 * (sr + 8 * T)));
                *(bf16x4*)((char*)Vt + A) = c;
            }
        }

        // ---- softmax + exchange per active block ----
        bf16x8 pafA[2], pafB[2];
        if (actA) { SOFTMAX_EXCH(sA, mrunA, lrunA, oA, pafA, (j == qiA)); }
        if (actB) { SOFTMAX_EXCH(sB, mrunB, lrunB, oB, pafB, (j == qiB)); }

        // ---- issue next K loads (kreg dead since Kb write) ----
        if (t + 1 < nit) { LOAD_K(lo + t); }
        __syncthreads();   // all Kb/Vt reads of this iter done

        // ---- O += P * V for both blocks; vf read once, used twice ----
        __builtin_amdgcn_s_setprio(1);
        #pragma unroll
        for (int n = 0; n < 8; ++n) {
            f32x4 a = oA[n];
            f32x4 c = oB[n];
            #pragma unroll
            for (int kk = 0; kk < 2; ++kk) {
                const uint32_t Av = vt_swz((uint32_t)((16 * n + lr) * 128 + 64 * kk + 16 * lk));
                bf16x8 vf = *(const bf16x8*)((const char*)Vt + Av);
                if (actA) a = __builtin_amdgcn_mfma_f32_16x16x32_bf16(pafA[kk], vf, a, 0, 0, 0);
                if (actB) c = __builtin_amdgcn_mfma_f32_16x16x32_bf16(pafB[kk], vf, c, 0, 0, 0);
            }
            oA[n] = a;
            oB[n] = c;
        }
        __builtin_amdgcn_s_setprio(0);
    }

    // ---- epilogue: per-block l reduce + store ----
    #pragma unroll
    for (int blk = 0; blk < 2; ++blk) {
        float lt = blk ? lrunB : lrunA;
        lt += __shfl_xor(lt, 16);
        lt += __shfl_xor(lt, 32);
        const int qi = blk ? qiB : qiA;
        float* obase = out + bh_off + (size_t)(qi * 64 + wave * 16) * ROWSTRIDE;
        #pragma unroll
        for (int r = 0; r < 4; ++r) {
            const float inv = 1.0f / __shfl(lt, 4 * lk + r);
            float* orow = obase + (size_t)(4 * lk + r) * ROWSTRIDE;
            #pragma unroll
            for (int n = 0; n < 8; ++n) {
                orow[16 * n + lr] = (blk ? oB[n][r] : oA[n][r]) * inv;
            }
        }
    }
}

extern "C" void kernel_launch(void* const* d_in, const int* in_sizes, int n_in,
                              void* d_out, int out_size, void* d_ws, size_t ws_size,
                              hipStream_t stream) {
    const float* q = (const float*)d_in[0];
    const float* k = (const float*)d_in[1];
    const float* v = (const float*)d_in[2];
    float* out = (float*)d_out;
    sparse_attn_kernel<<<dim3(1024), dim3(256), 0, stream>>>(q, k, v, out);
}

// Round 10
// 105.626 us; speedup vs baseline: 1.5478x; 1.5478x over previous
//
#include <hip/hip_runtime.h>
#include <hip/hip_bf16.h>

// Block-sparse attention: B=2, S=4096, H=16, D=128, BS=64, LOCAL=8, GLOBAL=1.
// fp32 in/out, bf16 MFMA, flash online softmax (exp2 domain).
// Round 10: r8 body (105 us) with lgkm-only barriers. __syncthreads() drains
// vmcnt(0) -> full prefetch-latency stall at both barriers (K prefetch was
// issued right before barrier 2 with ZERO cover). Only LDS (lgkm) ordering is
// needed for correctness; global loads land in private registers and drain at
// first use (Kb write / Vt write), covered by PV / QK respectively.

typedef __bf16 bf16_t;
typedef bf16_t bf16x8 __attribute__((ext_vector_type(8)));
typedef bf16_t bf16x4 __attribute__((ext_vector_type(4)));
typedef float f32x4 __attribute__((ext_vector_type(4)));
typedef uint32_t u32x4 __attribute__((ext_vector_type(4)));

#define BSZ 64
#define DIM 128
#define NH 16
#define SEQ 4096
#define ROWSTRIDE (NH * DIM)

// LDS barrier with lgkm-only drain (global loads may stay in flight).
#define LGKM_BARRIER()                                          \
    do {                                                        \
        asm volatile("s_waitcnt lgkmcnt(0)" ::: "memory");      \
        __builtin_amdgcn_s_barrier();                           \
        __builtin_amdgcn_sched_barrier(0);                      \
    } while (0)

// Kb: [64][128] bf16, A = row*256 + col*2. Fold row low-3 bits into chunk bits.
__device__ __forceinline__ uint32_t kb_swz(uint32_t A) {
    return A ^ (((A >> 8) & 7u) << 4);
}
// Vt: [128][64] bf16, A = d*128 + k*2. Fold d bits so PV read (lanes vary d)
// spreads over 8 chunk slots per 16-lane phase.
__device__ __forceinline__ uint32_t vt_swz(uint32_t A) {
    return A ^ (((A >> 9) & 7u) << 4) ^ (((A >> 8) & 1u) << 6);
}

__global__ __launch_bounds__(256) void sparse_attn_kernel(
    const float* __restrict__ q, const float* __restrict__ k,
    const float* __restrict__ v, float* __restrict__ out)
{
    __shared__ __align__(16) bf16_t Kb[BSZ * DIM];      // 16384 B
    __shared__ __align__(16) bf16_t Vt[DIM * BSZ];      // 16384 B (total 32768)

    // XCD-aware swizzle: 2048 wgs, 8 XCDs -> contiguous 256-chunk per XCD.
    const int L  = ((blockIdx.x & 7) << 8) | (blockIdx.x >> 3);
    const int qi = L & 63;
    const int h  = (L >> 6) & 15;
    const int b  = L >> 10;

    const int tid  = threadIdx.x;
    const int wave = tid >> 6;
    const int lane = tid & 63;
    const int lr = lane & 15;
    const int lk = lane >> 4;
    const int k0 = lk * 8;

    const int sc4 = tid & 31;   // staging: float4 column 0..31
    const int sr  = tid >> 5;   // staging: row group 0..7

    const float scale2 = 0.12751649736230476f;  // (1/sqrt(128)) * log2(e)

    const size_t bh_off = ((size_t)b * SEQ * NH + (size_t)h) * DIM;
    const float* kbh = k + bh_off;
    const float* vbh = v + bh_off;

    // ---- Q fragments, pre-scaled (wave owns q rows [qi*64+wave*16, +16)) ----
    bf16x8 qf[4];
    {
        const float* qrow = q + bh_off + (size_t)(qi * 64 + wave * 16 + lr) * ROWSTRIDE;
        #pragma unroll
        for (int kk = 0; kk < 4; ++kk) {
            const float4 a0 = *(const float4*)(qrow + 32 * kk + k0);
            const float4 a1 = *(const float4*)(qrow + 32 * kk + k0 + 4);
            bf16x8 f;
            f[0] = (bf16_t)(a0.x * scale2); f[1] = (bf16_t)(a0.y * scale2);
            f[2] = (bf16_t)(a0.z * scale2); f[3] = (bf16_t)(a0.w * scale2);
            f[4] = (bf16_t)(a1.x * scale2); f[5] = (bf16_t)(a1.y * scale2);
            f[6] = (bf16_t)(a1.z * scale2); f[7] = (bf16_t)(a1.w * scale2);
            qf[kk] = f;
        }
    }

    f32x4 oacc[8];
    #pragma unroll
    for (int n = 0; n < 8; ++n) oacc[n] = (f32x4){0.f, 0.f, 0.f, 0.f};
    float mrun = -3.0e38f, lrun = 0.f;   // per-lane: this lane's q-row is lr

    const int qrow_local = wave * 16 + lr;  // q position within the 64-block
    const int nnz = (qi < 8) ? (qi + 1) : 9;

    float4 kreg[8];   // K row (8i+sr), cols 4*sc4..+3   (one iter ahead)
    float4 vreg[8];   // V row 4*(sr+8*T)+i, cols 4*sc4..+3  (same iter)

    #define LOAD_K(jb)                                                            \
    {                                                                             \
        const float* kb_ = kbh + (size_t)((jb) * 64) * ROWSTRIDE + 4 * sc4;       \
        _Pragma("unroll")                                                         \
        for (int i = 0; i < 8; ++i)                                               \
            kreg[i] = *(const float4*)(kb_ + (size_t)(8 * i + sr) * ROWSTRIDE);   \
    }
    #define LOAD_V(jb)                                                            \
    {                                                                             \
        const float* vb_ = vbh + (size_t)((jb) * 64) * ROWSTRIDE + 4 * sc4;       \
        _Pragma("unroll")                                                         \
        for (int T = 0; T < 2; ++T)                                               \
            _Pragma("unroll")                                                     \
            for (int i = 0; i < 4; ++i)                                           \
                vreg[T * 4 + i] = *(const float4*)(vb_ +                          \
                    (size_t)(4 * (sr + 8 * T) + i) * ROWSTRIDE);                  \
    }

    LOAD_K(0);  // j_of(0) == 0 for every qi

    for (int t = 0; t < nnz; ++t) {
        const int j = (qi < 8) ? t : ((t == 0) ? 0 : (qi - 8 + t));

        // ---- issue V loads for THIS block (drain at Vt write, post-QK) ----
        LOAD_V(j);

        // ---- Kb write from kreg (compiler vmcnt waits only the K loads) ----
        #pragma unroll
        for (int i = 0; i < 8; ++i) {
            const float4 t4 = kreg[i];
            bf16x4 c = {(bf16_t)t4.x, (bf16_t)t4.y, (bf16_t)t4.z, (bf16_t)t4.w};
            const uint32_t A = kb_swz((uint32_t)((8 * i + sr) * 256 + 8 * sc4));
            *(bf16x4*)((char*)Kb + A) = c;
        }
        LGKM_BARRIER();   // Kb visible; V loads stay in flight

        // ---- S^T = K*Q^T: lane holds S[k=16n+4lk+r][q=lr] (exp2 domain) ----
        f32x4 sacc[4];
        __builtin_amdgcn_s_setprio(1);
        #pragma unroll
        for (int n = 0; n < 4; ++n) {
            f32x4 a = (f32x4){0.f, 0.f, 0.f, 0.f};
            #pragma unroll
            for (int kk = 0; kk < 4; ++kk) {
                const uint32_t A = kb_swz((uint32_t)((16 * n + lr) * 256 + 64 * kk + 16 * lk));
                bf16x8 kf = *(const bf16x8*)((const char*)Kb + A);
                a = __builtin_amdgcn_mfma_f32_16x16x32_bf16(kf, qf[kk], a, 0, 0, 0);
            }
            sacc[n] = a;
        }
        __builtin_amdgcn_s_setprio(0);

        // ---- Vt write from vreg (vreg dies here) ----
        #pragma unroll
        for (int T = 0; T < 2; ++T) {
            #pragma unroll
            for (int j2 = 0; j2 < 4; ++j2) {
                const int d = 4 * sc4 + j2;
                bf16x4 c = {(bf16_t)((const float*)&vreg[T * 4 + 0])[j2],
                            (bf16_t)((const float*)&vreg[T * 4 + 1])[j2],
                            (bf16_t)((const float*)&vreg[T * 4 + 2])[j2],
                            (bf16_t)((const float*)&vreg[T * 4 + 3])[j2]};
                const uint32_t A = vt_swz((uint32_t)(d * 128 + 8 * (sr + 8 * T)));
                *(bf16x4*)((char*)Vt + A) = c;
            }
        }

        // ---- mask (diag only) + row max (in-lane + 2 shfl) ----
        if (j == qi) {
            #pragma unroll
            for (int n = 0; n < 4; ++n)
                #pragma unroll
                for (int r = 0; r < 4; ++r) {
                    if (16 * n + 4 * lk + r > qrow_local) sacc[n][r] = -1.0e30f;
                }
        }
        float vmax = -3.0e38f;
        #pragma unroll
        for (int n = 0; n < 4; ++n)
            #pragma unroll
            for (int r = 0; r < 4; ++r) vmax = fmaxf(vmax, sacc[n][r]);
        vmax = fmaxf(vmax, __shfl_xor(vmax, 16));
        vmax = fmaxf(vmax, __shfl_xor(vmax, 32));

        // ---- online softmax (defer-max THR=8 log2), fully in-register ----
        if (!__all(vmax - mrun <= 8.0f)) {
            const float mnew = fmaxf(mrun, vmax);
            const float alpha = exp2f(mrun - mnew);
            mrun = mnew;
            lrun *= alpha;
            float av[4];
            #pragma unroll
            for (int r = 0; r < 4; ++r) av[r] = __shfl(alpha, 4 * lk + r);
            #pragma unroll
            for (int n = 0; n < 8; ++n)
                #pragma unroll
                for (int r = 0; r < 4; ++r) oacc[n][r] *= av[r];
        }
        // p + pack to bf16 chunks: ch[2n],ch[2n+1] = P[q=lr][k=16n+4lk + 0..3]
        uint32_t ch[8];
        #pragma unroll
        for (int n = 0; n < 4; ++n) {
            float p0 = exp2f(sacc[n][0] - mrun);
            float p1 = exp2f(sacc[n][1] - mrun);
            float p2 = exp2f(sacc[n][2] - mrun);
            float p3 = exp2f(sacc[n][3] - mrun);
            lrun += (p0 + p1) + (p2 + p3);
            bf16x4 c4 = {(bf16_t)p0, (bf16_t)p1, (bf16_t)p2, (bf16_t)p3};
            uint32_t* cw = (uint32_t*)&c4;
            ch[2 * n]     = cw[0];
            ch[2 * n + 1] = cw[1];
        }

        // ---- register exchange: build PV A-frags P[q=lr][k=32kk+8lk..+7] ----
        // dest (lr,lk) takes chunk[2kk+(lk>>1)] from lane lr+32*(lk&1)+16*delta
        bf16x8 paf[2];
        {
            const int s0 = lr + 32 * (lk & 1);
            const bool hi = (lk & 2) != 0;
            #pragma unroll
            for (int kk = 0; kk < 2; ++kk) {
                uint32_t res[4];
                #pragma unroll
                for (int u = 0; u < 2; ++u) {
                    const uint32_t a0 = (uint32_t)__shfl((int)ch[4 * kk + u],     s0);
                    const uint32_t b0 = (uint32_t)__shfl((int)ch[4 * kk + 2 + u], s0);
                    const uint32_t a1 = (uint32_t)__shfl((int)ch[4 * kk + u],     s0 + 16);
                    const uint32_t b1 = (uint32_t)__shfl((int)ch[4 * kk + 2 + u], s0 + 16);
                    res[u]     = hi ? b0 : a0;
                    res[2 + u] = hi ? b1 : a1;
                }
                u32x4 tv = {res[0], res[1], res[2], res[3]};
                paf[kk] = *(bf16x8*)&tv;
            }
        }

        // ---- issue next K loads; they stay in flight across the barrier ----
        if (t + 1 < nnz) {
            const int jn = (qi < 8) ? (t + 1) : (qi - 8 + t + 1);
            LOAD_K(jn);
        }
        LGKM_BARRIER();   // Vt visible + this wave's Kb reads done; K loads in flight

        // ---- O += P * V ----
        __builtin_amdgcn_s_setprio(1);
        #pragma unroll
        for (int n = 0; n < 8; ++n) {
            f32x4 a = oacc[n];
            #pragma unroll
            for (int kk = 0; kk < 2; ++kk) {
                const uint32_t Av = vt_swz((uint32_t)((16 * n + lr) * 128 + 64 * kk + 16 * lk));
                bf16x8 vf = *(const bf16x8*)((const char*)Vt + Av);
                a = __builtin_amdgcn_mfma_f32_16x16x32_bf16(paf[kk], vf, a, 0, 0, 0);
            }
            oacc[n] = a;
        }
        __builtin_amdgcn_s_setprio(0);
    }

    // ---- epilogue: total l per q-row, redistribute to oacc rows, store ----
    float lrtot = lrun;
    lrtot += __shfl_xor(lrtot, 16);
    lrtot += __shfl_xor(lrtot, 32);
    float* obase = out + bh_off + (size_t)(qi * 64 + wave * 16) * ROWSTRIDE;
    #pragma unroll
    for (int r = 0; r < 4; ++r) {
        const float inv = 1.0f / __shfl(lrtot, 4 * lk + r);
        float* orow = obase + (size_t)(4 * lk + r) * ROWSTRIDE;
        #pragma unroll
        for (int n = 0; n < 8; ++n) {
            orow[16 * n + lr] = oacc[n][r] * inv;
        }
    }
}

extern "C" void kernel_launch(void* const* d_in, const int* in_sizes, int n_in,
                              void* d_out, int out_size, void* d_ws, size_t ws_size,
                              hipStream_t stream) {
    const float* q = (const float*)d_in[0];
    const float* k = (const float*)d_in[1];
    const float* v = (const float*)d_in[2];
    float* out = (float*)d_out;
    sparse_attn_kernel<<<dim3(2048), dim3(256), 0, stream>>>(q, k, v, out);
}